// Round 3
// baseline (1009.962 us; speedup 1.0000x reference)
//
#include <hip/hip_runtime.h>
#include <hip/hip_bf16.h>

#define NN 768
#define NSQ (768*768)
#define CS 384
#define CZ 128
#define HH 12
#define INF_ 1e5f
#define EPS_ 1e-8f
#define LN_EPS_ 1e-5f

typedef __attribute__((ext_vector_type(8))) short short8;
typedef __attribute__((ext_vector_type(4))) short short4_t;
typedef __attribute__((ext_vector_type(4))) float floatx4;

// ---- workspace layout (float element offsets) ----
constexpr size_t OFF_SLN  = 0;                          // 768*384
constexpr size_t OFF_PROJ = OFF_SLN + (size_t)768*384;  // 768*1152 : [q|k|v|qp|kp|vp]
constexpr size_t OFF_QPG  = OFF_PROJ + (size_t)768*1152;// 768*144
constexpr size_t OFF_KPG  = OFF_QPG + (size_t)768*144;  // 768*144
constexpr size_t OFF_VPG  = OFF_KPG + (size_t)768*144;  // 768*288
constexpr size_t OFF_WTBF = OFF_VPG + (size_t)768*288;  // 48*128 bf16
constexpr size_t OFF_HW   = OFF_WTBF + 4096;            // 16
constexpr size_t OFF_ATT  = OFF_HW + 16;                // 12*NSQ
constexpr size_t OFF_PZ   = OFF_ATT + (size_t)12*NSQ;   // NSQ*32
constexpr size_t OFF_OCAT = OFF_PZ + (size_t)NSQ*32;    // 768*960
constexpr size_t OFF_VT   = OFF_OCAT + (size_t)768*960; // 480*768 transposed [v|vp]

__device__ __forceinline__ unsigned short f2bf(float f){
    unsigned int u = __float_as_uint(f);
    u = (u + 0x7fffu + ((u >> 16) & 1u)) >> 16;
    return (unsigned short)u;
}

// ---- K0: zero ocat + zero out + bf16 W^T + softplus(head_weights)
__global__ __launch_bounds__(256) void k_setup(const float* __restrict__ Wb, const float* __restrict__ Wdz,
                                               const float* __restrict__ hwin, float* __restrict__ ws,
                                               float* __restrict__ out){
    int b = blockIdx.x, t = threadIdx.x;
    if (b < 2880){ ws[OFF_OCAT + (size_t)b*256 + t] = 0.f; return; }
    b -= 2880;
    if (b < 1152){ out[(size_t)b*256 + t] = 0.f; return; }
    b -= 1152;
    if (b < 24){
        unsigned short* wt = (unsigned short*)(ws + OFF_WTBF);
        int o = b*2 + (t>>7), k = t & 127;
        float v = 0.f;
        if (o < HH) v = Wb[k*HH + o];
        else if (o < 44) v = Wdz[k*32 + (o - HH)];
        wt[o*128 + k] = f2bf(v);
        return;
    }
    b -= 24;
    if (b == 0 && t < HH){
        ws[OFF_HW + t] = log1pf(expf(hwin[t])) * sqrtf(1.0f/54.0f);
    }
}

// ---- K1: LayerNorm(s)
__global__ __launch_bounds__(128) void k_lns(const float* __restrict__ s, const float* __restrict__ g,
                                             const float* __restrict__ b, float* __restrict__ ws){
    int i = blockIdx.x, t = threadIdx.x;
    const float* row = s + (size_t)i*CS;
    float x0 = row[t], x1 = row[t+128], x2 = row[t+256];
    float sum = x0+x1+x2, sq = x0*x0+x1*x1+x2*x2;
    for (int off = 32; off; off >>= 1){ sum += __shfl_down(sum, off, 64); sq += __shfl_down(sq, off, 64); }
    __shared__ float ls[2][2];
    int w = t >> 6;
    if ((t & 63) == 0){ ls[w][0] = sum; ls[w][1] = sq; }
    __syncthreads();
    sum = ls[0][0] + ls[1][0]; sq = ls[0][1] + ls[1][1];
    float mu = sum * (1.0f/CS);
    float var = sq * (1.0f/CS) - mu*mu;
    float rstd = rsqrtf(var + LN_EPS_);
    float* outp = ws + OFF_SLN + (size_t)i*CS;
    outp[t]     = (x0-mu)*rstd*g[t]     + b[t];
    outp[t+128] = (x1-mu)*rstd*g[t+128] + b[t+128];
    outp[t+256] = (x2-mu)*rstd*g[t+256] + b[t+256];
}

// ---- K2: projections, s_ln (768x384) @ W (384x1152)
__global__ __launch_bounds__(256) void k_proj(const float* __restrict__ Wq, const float* __restrict__ Wk,
                                              const float* __restrict__ Wv, const float* __restrict__ Wqp,
                                              const float* __restrict__ Wkp, const float* __restrict__ Wvp,
                                              float* __restrict__ ws){
    __shared__ float slds[16][CS];
    const float* sln = ws + OFF_SLN;
    int rt = blockIdx.x, ct = blockIdx.y, t = threadIdx.x;
    for (int ix = t; ix < 16*CS; ix += 256){
        int r = ix / CS, c = ix % CS;
        slds[r][c] = sln[(size_t)(rt*16 + r)*CS + c];
    }
    __syncthreads();
    int col = ct*128 + (t & 127);
    int rg = t >> 7;
    const float* wp; int stride;
    if      (col < 192){ wp = Wq  + col;       stride = 192; }
    else if (col < 384){ wp = Wk  + (col-192); stride = 192; }
    else if (col < 576){ wp = Wv  + (col-384); stride = 192; }
    else if (col < 720){ wp = Wqp + (col-576); stride = 144; }
    else if (col < 864){ wp = Wkp + (col-720); stride = 144; }
    else               { wp = Wvp + (col-864); stride = 288; }
    float acc[8] = {0,0,0,0,0,0,0,0};
    for (int k = 0; k < CS; k += 4){
        float w0 = wp[(size_t)k*stride];
        float w1 = wp[(size_t)(k+1)*stride];
        float w2 = wp[(size_t)(k+2)*stride];
        float w3 = wp[(size_t)(k+3)*stride];
        #pragma unroll
        for (int r = 0; r < 8; r++){
            floatx4 sv = *(const floatx4*)&slds[rg*8+r][k];
            acc[r] += sv[0]*w0 + sv[1]*w1 + sv[2]*w2 + sv[3]*w3;
        }
    }
    float* proj = ws + OFF_PROJ;
    for (int r = 0; r < 8; r++) proj[(size_t)(rt*16 + rg*8 + r)*1152 + col] = acc[r];
}

// ---- K2b: points to global frame
__global__ __launch_bounds__(192) void k_pts(const float* __restrict__ rot, const float* __restrict__ trans,
                                             float* __restrict__ ws){
    int i = blockIdx.x, p = threadIdx.x;
    const float* proj = ws + OFF_PROJ + (size_t)i*1152;
    const float* src; float* dst;
    if (p < 48)      { src = proj + 576 + p*3;       dst = ws + OFF_QPG + (size_t)i*144 + p*3; }
    else if (p < 96) { src = proj + 720 + (p-48)*3;  dst = ws + OFF_KPG + (size_t)i*144 + (p-48)*3; }
    else             { src = proj + 864 + (p-96)*3;  dst = ws + OFF_VPG + (size_t)i*288 + (p-96)*3; }
    float x = src[0], y = src[1], z = src[2];
    const float* R = rot + (size_t)i*9;
    const float* T = trans + (size_t)i*3;
    dst[0] = R[0]*x + R[1]*y + R[2]*z + T[0];
    dst[1] = R[3]*x + R[4]*y + R[5]*z + T[1];
    dst[2] = R[6]*x + R[7]*y + R[8]*z + T[2];
}

// ---- K2c: transpose [v(192 via h*16+c) | vp_global(288 via h*24+c)] -> vT[480][768]
__global__ __launch_bounds__(256) void k_vt(float* __restrict__ ws){
    __shared__ float tile[32][33];
    int it = blockIdx.x, ut = blockIdx.y, t = threadIdx.x;
    const float* proj = ws + OFF_PROJ;
    const float* vpg  = ws + OFF_VPG;
    for (int ix = t; ix < 32*32; ix += 256){
        int r = ix >> 5, cu = ix & 31;
        int i = it*32 + r, u = ut*32 + cu;
        int h = u / 40, cc = u % 40;
        tile[r][cu] = (cc < 16) ? proj[(size_t)i*1152 + 384 + h*16 + cc]
                                : vpg[(size_t)i*288 + h*24 + (cc - 16)];
    }
    __syncthreads();
    float* vt = ws + OFF_VT;
    for (int ix = t; ix < 32*32; ix += 256){
        int cu = ix >> 5, r = ix & 31;
        int i = it*32 + r, u = ut*32 + cu;
        vt[(size_t)u*768 + i] = tile[r][cu];
    }
}

// ---- K3: LN(z) + [Wb|Wdz] via bf16 MFMA, coalesced loads
__global__ __launch_bounds__(256) void k_z(const float* __restrict__ z, const float* __restrict__ gz,
                                           const float* __restrict__ bz, float* __restrict__ ws){
    __shared__ unsigned short zlds[64][136];
    int t = threadIdx.x;
    int pb = blockIdx.x * 64;
    int lane32 = t & 31;
    int col = lane32 * 4;
    floatx4 g4 = *(const floatx4*)(gz + col);
    floatx4 b4 = *(const floatx4*)(bz + col);
    const float* zbase = z + (size_t)pb * 128;
    #pragma unroll
    for (int g = 0; g < 8; g++){
        int row = g*8 + (t >> 5);
        floatx4 v = *(const floatx4*)(zbase + (size_t)g*1024 + (size_t)t*4);
        float sum = v[0]+v[1]+v[2]+v[3];
        float sq  = v[0]*v[0]+v[1]*v[1]+v[2]*v[2]+v[3]*v[3];
        #pragma unroll
        for (int off = 1; off <= 16; off <<= 1){
            sum += __shfl_xor(sum, off, 64);
            sq  += __shfl_xor(sq , off, 64);
        }
        float mu = sum * (1.0f/128.0f);
        float rstd = rsqrtf(sq*(1.0f/128.0f) - mu*mu + LN_EPS_);
        short4_t sv;
        sv[0] = (short)f2bf((v[0]-mu)*rstd*g4[0] + b4[0]);
        sv[1] = (short)f2bf((v[1]-mu)*rstd*g4[1] + b4[1]);
        sv[2] = (short)f2bf((v[2]-mu)*rstd*g4[2] + b4[2]);
        sv[3] = (short)f2bf((v[3]-mu)*rstd*g4[3] + b4[3]);
        *(short4_t*)&zlds[row][col] = sv;
    }
    __syncthreads();
    const unsigned short* wt = (const unsigned short*)(ws + OFF_WTBF);
    int lane = t & 63, wv = t >> 6;
    int m = lane & 15, quad = lane >> 4;
    short8 bfrag[3][4];
    #pragma unroll
    for (int ot = 0; ot < 3; ot++)
        #pragma unroll
        for (int ks = 0; ks < 4; ks++){
            int o = ot*16 + m;
            bfrag[ot][ks] = *(const short8*)(wt + o*128 + ks*32 + quad*8);
        }
    floatx4 acc[3] = {{0.f,0.f,0.f,0.f},{0.f,0.f,0.f,0.f},{0.f,0.f,0.f,0.f}};
    int rbase = wv*16;
    #pragma unroll
    for (int ks = 0; ks < 4; ks++){
        short8 a = *(const short8*)&zlds[rbase + m][ks*32 + quad*8];
        acc[0] = __builtin_amdgcn_mfma_f32_16x16x32_bf16(a, bfrag[0][ks], acc[0], 0, 0, 0);
        acc[1] = __builtin_amdgcn_mfma_f32_16x16x32_bf16(a, bfrag[1][ks], acc[1], 0, 0, 0);
        acc[2] = __builtin_amdgcn_mfma_f32_16x16x32_bf16(a, bfrag[2][ks], acc[2], 0, 0, 0);
    }
    float* bias = ws + OFF_ATT;
    float* pz   = ws + OFF_PZ;
    #pragma unroll
    for (int ot = 0; ot < 3; ot++){
        int o = ot*16 + m;
        #pragma unroll
        for (int rg = 0; rg < 4; rg++){
            int pair = pb + rbase + quad*4 + rg;
            float val = acc[ot][rg];
            if (o < HH)      bias[(size_t)o*NSQ + pair] = val;
            else if (o < 44) pz[(size_t)pair*32 + (o - HH)] = val;
        }
    }
}

// ---- K4: logits (in place over bias buffer); k-side float2 @ stride 338 (2-way = free)
__global__ __launch_bounds__(256) void k_logits(const float* __restrict__ smask, const int* __restrict__ idx,
                                                float* __restrict__ ws){
    __shared__ float qlds[8][336];
    __shared__ float klds[32][338];
    int it = blockIdx.x, jt = blockIdx.y, t = threadIdx.x;
    const float* proj = ws + OFF_PROJ;
    const float* qpg  = ws + OFF_QPG;
    const float* kpg  = ws + OFF_KPG;
    const float* hw   = ws + OFF_HW;
    float* att = ws + OFF_ATT;
    for (int ix = t; ix < 8*336; ix += 256){
        int r = ix / 336, c = ix % 336;
        int i = it*8 + r;
        qlds[r][c] = (c < 192) ? proj[(size_t)i*1152 + c] : qpg[(size_t)i*144 + (c - 192)];
    }
    for (int ix = t; ix < 32*336; ix += 256){
        int r = ix / 336, c = ix % 336;
        int j = jt*32 + r;
        klds[r][c] = (c < 192) ? proj[(size_t)j*1152 + 192 + c] : kpg[(size_t)j*144 + (c - 192)];
    }
    __syncthreads();
    int jl = t & 31, grp = t >> 5;
    int i = it*8 + grp, j = jt*32 + jl;
    int ires = idx[i], jres = idx[j];
    float mterm = INF_ * (smask[ires]*smask[jres] - 1.0f);
    const float S1 = 0.14433756729740643f;
    const float S2 = 0.57735026918962576f;
    for (int h = 0; h < HH; h++){
        floatx4 q0 = *(const floatx4*)&qlds[grp][h*16];
        floatx4 q1 = *(const floatx4*)&qlds[grp][h*16+4];
        floatx4 q2 = *(const floatx4*)&qlds[grp][h*16+8];
        floatx4 q3 = *(const floatx4*)&qlds[grp][h*16+12];
        const float* kr = &klds[jl][h*16];
        float2 k0 = *(const float2*)(kr+0),  k1 = *(const float2*)(kr+2);
        float2 k2 = *(const float2*)(kr+4),  k3 = *(const float2*)(kr+6);
        float2 k4 = *(const float2*)(kr+8),  k5 = *(const float2*)(kr+10);
        float2 k6 = *(const float2*)(kr+12), k7 = *(const float2*)(kr+14);
        float qk = q0[0]*k0.x+q0[1]*k0.y+q0[2]*k1.x+q0[3]*k1.y
                 + q1[0]*k2.x+q1[1]*k2.y+q1[2]*k3.x+q1[3]*k3.y
                 + q2[0]*k4.x+q2[1]*k4.y+q2[2]*k5.x+q2[3]*k5.y
                 + q3[0]*k6.x+q3[1]*k6.y+q3[2]*k7.x+q3[3]*k7.y;
        floatx4 qp0 = *(const floatx4*)&qlds[grp][192+h*12];
        floatx4 qp1 = *(const floatx4*)&qlds[grp][192+h*12+4];
        floatx4 qp2 = *(const floatx4*)&qlds[grp][192+h*12+8];
        const float* kp = &klds[jl][192+h*12];
        float2 p0 = *(const float2*)(kp+0), p1 = *(const float2*)(kp+2);
        float2 p2 = *(const float2*)(kp+4), p3 = *(const float2*)(kp+6);
        float2 p4 = *(const float2*)(kp+8), p5 = *(const float2*)(kp+10);
        float d0 = qp0[0]-p0.x, d1 = qp0[1]-p0.y, d2a = qp0[2]-p1.x, d3 = qp0[3]-p1.y;
        float d4 = qp1[0]-p2.x, d5 = qp1[1]-p2.y, d6 = qp1[2]-p3.x, d7 = qp1[3]-p3.y;
        float d8 = qp2[0]-p4.x, d9 = qp2[1]-p4.y, dA = qp2[2]-p5.x, dB = qp2[3]-p5.y;
        float d2 = d0*d0+d1*d1+d2a*d2a+d3*d3 + d4*d4+d5*d5+d6*d6+d7*d7 + d8*d8+d9*d9+dA*dA+dB*dB;
        float bv = att[(size_t)h*NSQ + (size_t)ires*NN + jres];
        float lg = qk*S1 + S2*(bv + mterm) - 0.5f*hw[h]*d2;
        att[(size_t)h*NSQ + (size_t)i*NN + j] = lg;
    }
}

// ---- K4c: softmax over j, float4
__global__ __launch_bounds__(192) void k_softmax(float* __restrict__ ws){
    int b = blockIdx.x, t = threadIdx.x;
    float* row = ws + OFF_ATT + (size_t)b*NN;
    floatx4 v = *(floatx4*)(row + t*4);
    float mx = fmaxf(fmaxf(v[0],v[1]), fmaxf(v[2],v[3]));
    for (int off = 32; off; off >>= 1) mx = fmaxf(mx, __shfl_xor(mx, off, 64));
    __shared__ float lsm[3];
    __shared__ float lss[3];
    int w = t >> 6;
    if ((t & 63) == 0) lsm[w] = mx;
    __syncthreads();
    mx = fmaxf(fmaxf(lsm[0], lsm[1]), lsm[2]);
    floatx4 e;
    e[0] = expf(v[0]-mx); e[1] = expf(v[1]-mx); e[2] = expf(v[2]-mx); e[3] = expf(v[3]-mx);
    float s = e[0]+e[1]+e[2]+e[3];
    for (int off = 32; off; off >>= 1) s += __shfl_xor(s, off, 64);
    if ((t & 63) == 0) lss[w] = s;
    __syncthreads();
    s = lss[0] + lss[1] + lss[2];
    float inv = 1.0f / s;
    e[0] *= inv; e[1] *= inv; e[2] *= inv; e[3] *= inv;
    *(floatx4*)(row + t*4) = e;
}

// ---- K5: o & o_pt(global): per (h, 32-i-tile, j-third). 4x5 register tile per thread.
__global__ __launch_bounds__(256) void k_ov(float* __restrict__ ws){
    __shared__ float plds[32][130];
    __shared__ float wldsT[40][132];   // reused as reduction scratch (5280 >= 5120 floats)
    int h = blockIdx.x, it = blockIdx.y, zs = blockIdx.z, t = threadIdx.x;
    const float* att = ws + OFF_ATT + (size_t)h*NSQ;
    const float* vt  = ws + OFF_VT + (size_t)h*40*768;
    int c8 = t & 7, ig = (t>>3)&7, jq = t>>6;
    float acc[4][5];
    #pragma unroll
    for (int r=0;r<4;r++){ acc[r][0]=0;acc[r][1]=0;acc[r][2]=0;acc[r][3]=0;acc[r][4]=0; }
    for (int jt = zs*2; jt < zs*2+2; jt++){
        __syncthreads();
        for (int ix = t; ix < 32*128; ix += 256){
            int rr = ix>>7, jj = ix&127;
            plds[rr][jj] = att[(size_t)(it*32+rr)*NN + jt*128 + jj];
        }
        for (int ix = t; ix < 40*128; ix += 256){
            int cc = ix>>7, jj = ix&127;
            wldsT[cc][jj] = vt[(size_t)cc*768 + jt*128 + jj];
        }
        __syncthreads();
        int j0 = jq*32;
        for (int ch = 0; ch < 8; ch++){
            int jj = j0 + ch*4;
            float2 pa[4], pb[4];
            #pragma unroll
            for (int r=0;r<4;r++){
                pa[r] = *(const float2*)&plds[ig*4+r][jj];
                pb[r] = *(const float2*)&plds[ig*4+r][jj+2];
            }
            #pragma unroll
            for (int q=0;q<5;q++){
                floatx4 wv = *(const floatx4*)&wldsT[c8*5+q][jj];
                #pragma unroll
                for (int r=0;r<4;r++)
                    acc[r][q] += pa[r].x*wv[0] + pa[r].y*wv[1] + pb[r].x*wv[2] + pb[r].y*wv[3];
            }
        }
    }
    __syncthreads();
    float* scratch = &wldsT[0][0];
    #pragma unroll
    for (int r=0;r<4;r++)
        #pragma unroll
        for (int q=0;q<5;q++) scratch[t*20 + r*5 + q] = acc[r][q];
    __syncthreads();
    if (t < 64){
        float* ocat = ws + OFF_OCAT;
        #pragma unroll
        for (int r=0;r<4;r++){
            int i = it*32 + ig*4 + r;
            #pragma unroll
            for (int q=0;q<5;q++){
                float v = scratch[t*20+r*5+q] + scratch[(t+64)*20+r*5+q]
                        + scratch[(t+128)*20+r*5+q] + scratch[(t+192)*20+r*5+q];
                int c = c8*5 + q;
                int col = (c < 16) ? (h*16 + c) : (576 + h*24 + (c - 16));
                atomicAdd(&ocat[(size_t)i*960 + col], v);
            }
        }
    }
}

// ---- K6: o_pair: per i, 4x4 register tile (h-group x c-group), j split 16 ways
__global__ __launch_bounds__(384) void k_opair(const int* __restrict__ idx, float* __restrict__ ws){
    __shared__ float plds[12][132];
    __shared__ float pzT[32][130];
    __shared__ float scratch[384*16];
    int i = blockIdx.x, t = threadIdx.x;
    int ires = idx[i];
    int jq = t & 15, cg = (t>>4)&7, hg = t>>7;
    float acc[4][4];
    #pragma unroll
    for (int r=0;r<4;r++){ acc[r][0]=0;acc[r][1]=0;acc[r][2]=0;acc[r][3]=0; }
    const float* pzg = ws + OFF_PZ + (size_t)ires*NN*32;
    const float* att = ws + OFF_ATT;
    for (int jt = 0; jt < 6; jt++){
        __syncthreads();
        for (int ix = t; ix < 12*128; ix += 384){
            int hh = ix>>7, jj = ix&127;
            plds[hh][jj] = att[(size_t)hh*NSQ + (size_t)i*NN + jt*128 + jj];
        }
        for (int ix = t; ix < 32*128; ix += 384){
            int jj = ix>>5, cc = ix&31;
            int jres = idx[jt*128 + jj];
            pzT[cc][jj] = pzg[(size_t)jres*32 + cc];
        }
        __syncthreads();
        #pragma unroll
        for (int ch = 0; ch < 2; ch++){
            int jj = jq*8 + ch*4;
            floatx4 p[4];
            #pragma unroll
            for (int r=0;r<4;r++) p[r] = *(const floatx4*)&plds[hg*4+r][jj];
            #pragma unroll
            for (int q=0;q<4;q++){
                int cc = q*8 + cg;
                float2 z0 = *(const float2*)&pzT[cc][jj];
                float2 z1 = *(const float2*)&pzT[cc][jj+2];
                #pragma unroll
                for (int r=0;r<4;r++)
                    acc[r][q] += p[r][0]*z0.x + p[r][1]*z0.y + p[r][2]*z1.x + p[r][3]*z1.y;
            }
        }
    }
    __syncthreads();
    #pragma unroll
    for (int r=0;r<4;r++)
        #pragma unroll
        for (int q=0;q<4;q++) scratch[t*16 + r*4 + q] = acc[r][q];
    __syncthreads();
    // 384 threads = 24 combos x 16 elems, each sums 16 jq-partials
    int combo = t >> 4, e = t & 15;
    int hg2 = combo >> 3, cg2 = combo & 7;
    float v = 0.f;
    #pragma unroll
    for (int p = 0; p < 16; p++) v += scratch[(hg2*128 + cg2*16 + p)*16 + e];
    int h = hg2*4 + (e >> 2);
    int cc = (e & 3)*8 + cg2;
    float* oc = ws + OFF_OCAT + (size_t)i*960 + 192;
    oc[h*32 + cc] = v;
}

// ---- K6b: o_pt local frame + norms
__global__ __launch_bounds__(96) void k_ptfin(const float* __restrict__ rot, const float* __restrict__ trans,
                                              float* __restrict__ ws){
    int i = blockIdx.x, p = threadIdx.x;
    float* base = ws + OFF_OCAT + (size_t)i*960;
    float* pt = base + 576 + p*3;
    float x = pt[0] - trans[i*3+0];
    float y = pt[1] - trans[i*3+1];
    float z = pt[2] - trans[i*3+2];
    const float* R = rot + (size_t)i*9;
    float lx = R[0]*x + R[3]*y + R[6]*z;
    float ly = R[1]*x + R[4]*y + R[7]*z;
    float lz = R[2]*x + R[5]*y + R[8]*z;
    pt[0] = lx; pt[1] = ly; pt[2] = lz;
    base[864 + p] = sqrtf(lx*lx + ly*ly + lz*lz + EPS_);
}

// ---- K7: final GEMM, k-split x4, 8x2 register tile, atomic into zeroed out
__global__ __launch_bounds__(256) void k_out(const float* __restrict__ Wout, const float* __restrict__ Woutb,
                                             const float* __restrict__ Woutp, float* __restrict__ ws,
                                             float* __restrict__ out){
    __shared__ float olds[32][244];
    int it = blockIdx.x, ct = blockIdx.y, kc = blockIdx.z, t = threadIdx.x;
    const float* ocat = ws + OFF_OCAT;
    for (int ix = t; ix < 32*240; ix += 256){
        int r = ix / 240, kk = ix % 240;
        olds[r][kk] = ocat[(size_t)(it*32 + r)*960 + kc*240 + kk];
    }
    __syncthreads();
    int cl = t & 63, ig = t >> 6;
    int c0 = ct*128 + cl, c1 = c0 + 64;
    float acc0[8], acc1[8];
    #pragma unroll
    for (int r=0;r<8;r++){ acc0[r]=0; acc1[r]=0; }
    for (int kk = 0; kk < 240; kk += 4){
        float w0[4], w1[4];
        #pragma unroll
        for (int u = 0; u < 4; u++){
            int k = kc*240 + kk + u;
            const float* wrow = (k < 192) ? (Wout  + (size_t)k*CS)
                              : (k < 576) ? (Woutb + (size_t)(k-192)*CS)
                                          : (Woutp + (size_t)(k-576)*CS);
            w0[u] = wrow[c0]; w1[u] = wrow[c1];
        }
        #pragma unroll
        for (int r = 0; r < 8; r++){
            floatx4 ov = *(const floatx4*)&olds[ig*8 + r][kk];
            acc0[r] += ov[0]*w0[0] + ov[1]*w0[1] + ov[2]*w0[2] + ov[3]*w0[3];
            acc1[r] += ov[0]*w1[0] + ov[1]*w1[1] + ov[2]*w1[2] + ov[3]*w1[3];
        }
    }
    for (int r = 0; r < 8; r++){
        int i = it*32 + ig*8 + r;
        atomicAdd(&out[(size_t)i*CS + c0], acc0[r]);
        atomicAdd(&out[(size_t)i*CS + c1], acc1[r]);
    }
}

extern "C" void kernel_launch(void* const* d_in, const int* in_sizes, int n_in,
                              void* d_out, int out_size, void* d_ws, size_t ws_size,
                              hipStream_t stream){
    const float* s     = (const float*)d_in[0];
    const float* z     = (const float*)d_in[1];
    const float* rot   = (const float*)d_in[2];
    const float* trans = (const float*)d_in[3];
    const float* smask = (const float*)d_in[4];
    const float* gs    = (const float*)d_in[5];
    const float* bs    = (const float*)d_in[6];
    const float* gz    = (const float*)d_in[7];
    const float* bz    = (const float*)d_in[8];
    const float* Wq    = (const float*)d_in[9];
    const float* Wk    = (const float*)d_in[10];
    const float* Wv    = (const float*)d_in[11];
    const float* Wqp   = (const float*)d_in[12];
    const float* Wkp   = (const float*)d_in[13];
    const float* Wvp   = (const float*)d_in[14];
    const float* Wb    = (const float*)d_in[15];
    const float* Wdz   = (const float*)d_in[16];
    const float* hwin  = (const float*)d_in[17];
    const float* Wout  = (const float*)d_in[18];
    const float* Woutb = (const float*)d_in[19];
    const float* Woutp = (const float*)d_in[20];
    const int*   idx   = (const int*)d_in[21];
    float* ws  = (float*)d_ws;
    float* out = (float*)d_out;

    k_setup  <<<4057, 256, 0, stream>>>(Wb, Wdz, hwin, ws, out);
    k_lns    <<<768, 128, 0, stream>>>(s, gs, bs, ws);
    k_proj   <<<dim3(48, 9), 256, 0, stream>>>(Wq, Wk, Wv, Wqp, Wkp, Wvp, ws);
    k_pts    <<<768, 192, 0, stream>>>(rot, trans, ws);
    k_vt     <<<dim3(24, 15), 256, 0, stream>>>(ws);
    k_z      <<<9216, 256, 0, stream>>>(z, gz, bz, ws);
    k_logits <<<dim3(96, 24), 256, 0, stream>>>(smask, idx, ws);
    k_softmax<<<9216, 192, 0, stream>>>(ws);
    k_ov     <<<dim3(12, 24, 3), 256, 0, stream>>>(ws);
    k_opair  <<<768, 384, 0, stream>>>(idx, ws);
    k_ptfin  <<<768, 96, 0, stream>>>(rot, trans, ws);
    k_out    <<<dim3(24, 3, 4), 256, 0, stream>>>(Wout, Woutb, Woutp, ws, out);
}

// Round 4
// 840.748 us; speedup vs baseline: 1.2013x; 1.2013x over previous
//
#include <hip/hip_runtime.h>
#include <hip/hip_bf16.h>

#define NN 768
#define NSQ (768*768)
#define CS 384
#define CZ 128
#define HH 12
#define INF_ 1e5f
#define EPS_ 1e-8f
#define LN_EPS_ 1e-5f

typedef __attribute__((ext_vector_type(8))) short short8;
typedef __attribute__((ext_vector_type(4))) short short4_t;
typedef __attribute__((ext_vector_type(4))) float floatx4;

// ---- workspace layout (float element offsets) ----
constexpr size_t OFF_SLN  = 0;                          // 768*384
constexpr size_t OFF_PROJ = OFF_SLN + (size_t)768*384;  // 768*1152 : [q|k|v|qp|kp|vp]
constexpr size_t OFF_QPG  = OFF_PROJ + (size_t)768*1152;// 768*144
constexpr size_t OFF_KPG  = OFF_QPG + (size_t)768*144;  // 768*144
constexpr size_t OFF_VPG  = OFF_KPG + (size_t)768*144;  // 768*288
constexpr size_t OFF_WTBF = OFF_VPG + (size_t)768*288;  // 48*128 bf16
constexpr size_t OFF_HW   = OFF_WTBF + 4096;            // 16
constexpr size_t OFF_ATT  = OFF_HW + 16;                // 12*NSQ
constexpr size_t OFF_PZ   = OFF_ATT + (size_t)12*NSQ;   // NSQ*32
constexpr size_t OFF_OCAT = OFF_PZ + (size_t)NSQ*32;    // 768*960

__device__ __forceinline__ unsigned short f2bf(float f){
    unsigned int u = __float_as_uint(f);
    u = (u + 0x7fffu + ((u >> 16) & 1u)) >> 16;
    return (unsigned short)u;
}

// ---- K0: zero ocat + zero out + bf16 W^T + softplus(head_weights)
__global__ __launch_bounds__(256) void k_setup(const float* __restrict__ Wb, const float* __restrict__ Wdz,
                                               const float* __restrict__ hwin, float* __restrict__ ws,
                                               float* __restrict__ out){
    int b = blockIdx.x, t = threadIdx.x;
    if (b < 2880){ ws[OFF_OCAT + (size_t)b*256 + t] = 0.f; return; }
    b -= 2880;
    if (b < 1152){ out[(size_t)b*256 + t] = 0.f; return; }
    b -= 1152;
    if (b < 24){
        unsigned short* wt = (unsigned short*)(ws + OFF_WTBF);
        int o = b*2 + (t>>7), k = t & 127;
        float v = 0.f;
        if (o < HH) v = Wb[k*HH + o];
        else if (o < 44) v = Wdz[k*32 + (o - HH)];
        wt[o*128 + k] = f2bf(v);
        return;
    }
    b -= 24;
    if (b == 0 && t < HH){
        ws[OFF_HW + t] = log1pf(expf(hwin[t])) * sqrtf(1.0f/54.0f);
    }
}

// ---- K1: LayerNorm(s)
__global__ __launch_bounds__(128) void k_lns(const float* __restrict__ s, const float* __restrict__ g,
                                             const float* __restrict__ b, float* __restrict__ ws){
    int i = blockIdx.x, t = threadIdx.x;
    const float* row = s + (size_t)i*CS;
    float x0 = row[t], x1 = row[t+128], x2 = row[t+256];
    float sum = x0+x1+x2, sq = x0*x0+x1*x1+x2*x2;
    for (int off = 32; off; off >>= 1){ sum += __shfl_down(sum, off, 64); sq += __shfl_down(sq, off, 64); }
    __shared__ float ls[2][2];
    int w = t >> 6;
    if ((t & 63) == 0){ ls[w][0] = sum; ls[w][1] = sq; }
    __syncthreads();
    sum = ls[0][0] + ls[1][0]; sq = ls[0][1] + ls[1][1];
    float mu = sum * (1.0f/CS);
    float var = sq * (1.0f/CS) - mu*mu;
    float rstd = rsqrtf(var + LN_EPS_);
    float* outp = ws + OFF_SLN + (size_t)i*CS;
    outp[t]     = (x0-mu)*rstd*g[t]     + b[t];
    outp[t+128] = (x1-mu)*rstd*g[t+128] + b[t+128];
    outp[t+256] = (x2-mu)*rstd*g[t+256] + b[t+256];
}

// ---- K2: projections, s_ln (768x384) @ W (384x1152)
__global__ __launch_bounds__(256) void k_proj(const float* __restrict__ Wq, const float* __restrict__ Wk,
                                              const float* __restrict__ Wv, const float* __restrict__ Wqp,
                                              const float* __restrict__ Wkp, const float* __restrict__ Wvp,
                                              float* __restrict__ ws){
    __shared__ float slds[16][CS];
    const float* sln = ws + OFF_SLN;
    int rt = blockIdx.x, ct = blockIdx.y, t = threadIdx.x;
    for (int ix = t; ix < 16*CS; ix += 256){
        int r = ix / CS, c = ix % CS;
        slds[r][c] = sln[(size_t)(rt*16 + r)*CS + c];
    }
    __syncthreads();
    int col = ct*128 + (t & 127);
    int rg = t >> 7;
    const float* wp; int stride;
    if      (col < 192){ wp = Wq  + col;       stride = 192; }
    else if (col < 384){ wp = Wk  + (col-192); stride = 192; }
    else if (col < 576){ wp = Wv  + (col-384); stride = 192; }
    else if (col < 720){ wp = Wqp + (col-576); stride = 144; }
    else if (col < 864){ wp = Wkp + (col-720); stride = 144; }
    else               { wp = Wvp + (col-864); stride = 288; }
    float acc[8] = {0,0,0,0,0,0,0,0};
    for (int k = 0; k < CS; k += 4){
        float w0 = wp[(size_t)k*stride];
        float w1 = wp[(size_t)(k+1)*stride];
        float w2 = wp[(size_t)(k+2)*stride];
        float w3 = wp[(size_t)(k+3)*stride];
        #pragma unroll
        for (int r = 0; r < 8; r++){
            floatx4 sv = *(const floatx4*)&slds[rg*8+r][k];
            acc[r] += sv[0]*w0 + sv[1]*w1 + sv[2]*w2 + sv[3]*w3;
        }
    }
    float* proj = ws + OFF_PROJ;
    for (int r = 0; r < 8; r++) proj[(size_t)(rt*16 + rg*8 + r)*1152 + col] = acc[r];
}

// ---- K2b: points to global frame
__global__ __launch_bounds__(192) void k_pts(const float* __restrict__ rot, const float* __restrict__ trans,
                                             float* __restrict__ ws){
    int i = blockIdx.x, p = threadIdx.x;
    const float* proj = ws + OFF_PROJ + (size_t)i*1152;
    const float* src; float* dst;
    if (p < 48)      { src = proj + 576 + p*3;       dst = ws + OFF_QPG + (size_t)i*144 + p*3; }
    else if (p < 96) { src = proj + 720 + (p-48)*3;  dst = ws + OFF_KPG + (size_t)i*144 + (p-48)*3; }
    else             { src = proj + 864 + (p-96)*3;  dst = ws + OFF_VPG + (size_t)i*288 + (p-96)*3; }
    float x = src[0], y = src[1], z = src[2];
    const float* R = rot + (size_t)i*9;
    const float* T = trans + (size_t)i*3;
    dst[0] = R[0]*x + R[1]*y + R[2]*z + T[0];
    dst[1] = R[3]*x + R[4]*y + R[5]*z + T[1];
    dst[2] = R[6]*x + R[7]*y + R[8]*z + T[2];
}

// ---- K3: LN(z) + [Wb|Wdz] via bf16 MFMA, coalesced loads
__global__ __launch_bounds__(256) void k_z(const float* __restrict__ z, const float* __restrict__ gz,
                                           const float* __restrict__ bz, float* __restrict__ ws){
    __shared__ unsigned short zlds[64][136];
    int t = threadIdx.x;
    int pb = blockIdx.x * 64;
    int lane32 = t & 31;
    int col = lane32 * 4;
    floatx4 g4 = *(const floatx4*)(gz + col);
    floatx4 b4 = *(const floatx4*)(bz + col);
    const float* zbase = z + (size_t)pb * 128;
    #pragma unroll
    for (int g = 0; g < 8; g++){
        int row = g*8 + (t >> 5);
        floatx4 v = *(const floatx4*)(zbase + (size_t)g*1024 + (size_t)t*4);
        float sum = v[0]+v[1]+v[2]+v[3];
        float sq  = v[0]*v[0]+v[1]*v[1]+v[2]*v[2]+v[3]*v[3];
        #pragma unroll
        for (int off = 1; off <= 16; off <<= 1){
            sum += __shfl_xor(sum, off, 64);
            sq  += __shfl_xor(sq , off, 64);
        }
        float mu = sum * (1.0f/128.0f);
        float rstd = rsqrtf(sq*(1.0f/128.0f) - mu*mu + LN_EPS_);
        short4_t sv;
        sv[0] = (short)f2bf((v[0]-mu)*rstd*g4[0] + b4[0]);
        sv[1] = (short)f2bf((v[1]-mu)*rstd*g4[1] + b4[1]);
        sv[2] = (short)f2bf((v[2]-mu)*rstd*g4[2] + b4[2]);
        sv[3] = (short)f2bf((v[3]-mu)*rstd*g4[3] + b4[3]);
        *(short4_t*)&zlds[row][col] = sv;
    }
    __syncthreads();
    const unsigned short* wt = (const unsigned short*)(ws + OFF_WTBF);
    int lane = t & 63, wv = t >> 6;
    int m = lane & 15, quad = lane >> 4;
    short8 bfrag[3][4];
    #pragma unroll
    for (int ot = 0; ot < 3; ot++)
        #pragma unroll
        for (int ks = 0; ks < 4; ks++){
            int o = ot*16 + m;
            bfrag[ot][ks] = *(const short8*)(wt + o*128 + ks*32 + quad*8);
        }
    floatx4 acc[3] = {{0.f,0.f,0.f,0.f},{0.f,0.f,0.f,0.f},{0.f,0.f,0.f,0.f}};
    int rbase = wv*16;
    #pragma unroll
    for (int ks = 0; ks < 4; ks++){
        short8 a = *(const short8*)&zlds[rbase + m][ks*32 + quad*8];
        acc[0] = __builtin_amdgcn_mfma_f32_16x16x32_bf16(a, bfrag[0][ks], acc[0], 0, 0, 0);
        acc[1] = __builtin_amdgcn_mfma_f32_16x16x32_bf16(a, bfrag[1][ks], acc[1], 0, 0, 0);
        acc[2] = __builtin_amdgcn_mfma_f32_16x16x32_bf16(a, bfrag[2][ks], acc[2], 0, 0, 0);
    }
    float* bias = ws + OFF_ATT;
    float* pz   = ws + OFF_PZ;
    #pragma unroll
    for (int ot = 0; ot < 3; ot++){
        int o = ot*16 + m;
        #pragma unroll
        for (int rg = 0; rg < 4; rg++){
            int pair = pb + rbase + quad*4 + rg;
            float val = acc[ot][rg];
            if (o < HH)      bias[(size_t)o*NSQ + pair] = val;
            else if (o < 44) pz[(size_t)pair*32 + (o - HH)] = val;
        }
    }
}

// ---- K4: logits (in place over bias buffer); k-side float2 @ stride 338 (2-way = free)
__global__ __launch_bounds__(256) void k_logits(const float* __restrict__ smask, const int* __restrict__ idx,
                                                float* __restrict__ ws){
    __shared__ float qlds[8][336];
    __shared__ float klds[32][338];
    int it = blockIdx.x, jt = blockIdx.y, t = threadIdx.x;
    const float* proj = ws + OFF_PROJ;
    const float* qpg  = ws + OFF_QPG;
    const float* kpg  = ws + OFF_KPG;
    const float* hw   = ws + OFF_HW;
    float* att = ws + OFF_ATT;
    for (int ix = t; ix < 8*336; ix += 256){
        int r = ix / 336, c = ix % 336;
        int i = it*8 + r;
        qlds[r][c] = (c < 192) ? proj[(size_t)i*1152 + c] : qpg[(size_t)i*144 + (c - 192)];
    }
    for (int ix = t; ix < 32*336; ix += 256){
        int r = ix / 336, c = ix % 336;
        int j = jt*32 + r;
        klds[r][c] = (c < 192) ? proj[(size_t)j*1152 + 192 + c] : kpg[(size_t)j*144 + (c - 192)];
    }
    __syncthreads();
    int jl = t & 31, grp = t >> 5;
    int i = it*8 + grp, j = jt*32 + jl;
    int ires = idx[i], jres = idx[j];
    float mterm = INF_ * (smask[ires]*smask[jres] - 1.0f);
    const float S1 = 0.14433756729740643f;
    const float S2 = 0.57735026918962576f;
    for (int h = 0; h < HH; h++){
        floatx4 q0 = *(const floatx4*)&qlds[grp][h*16];
        floatx4 q1 = *(const floatx4*)&qlds[grp][h*16+4];
        floatx4 q2 = *(const floatx4*)&qlds[grp][h*16+8];
        floatx4 q3 = *(const floatx4*)&qlds[grp][h*16+12];
        const float* kr = &klds[jl][h*16];
        float2 k0 = *(const float2*)(kr+0),  k1 = *(const float2*)(kr+2);
        float2 k2 = *(const float2*)(kr+4),  k3 = *(const float2*)(kr+6);
        float2 k4 = *(const float2*)(kr+8),  k5 = *(const float2*)(kr+10);
        float2 k6 = *(const float2*)(kr+12), k7 = *(const float2*)(kr+14);
        float qk = q0[0]*k0.x+q0[1]*k0.y+q0[2]*k1.x+q0[3]*k1.y
                 + q1[0]*k2.x+q1[1]*k2.y+q1[2]*k3.x+q1[3]*k3.y
                 + q2[0]*k4.x+q2[1]*k4.y+q2[2]*k5.x+q2[3]*k5.y
                 + q3[0]*k6.x+q3[1]*k6.y+q3[2]*k7.x+q3[3]*k7.y;
        floatx4 qp0 = *(const floatx4*)&qlds[grp][192+h*12];
        floatx4 qp1 = *(const floatx4*)&qlds[grp][192+h*12+4];
        floatx4 qp2 = *(const floatx4*)&qlds[grp][192+h*12+8];
        const float* kp = &klds[jl][192+h*12];
        float2 p0 = *(const float2*)(kp+0), p1 = *(const float2*)(kp+2);
        float2 p2 = *(const float2*)(kp+4), p3 = *(const float2*)(kp+6);
        float2 p4 = *(const float2*)(kp+8), p5 = *(const float2*)(kp+10);
        float d0 = qp0[0]-p0.x, d1 = qp0[1]-p0.y, d2a = qp0[2]-p1.x, d3 = qp0[3]-p1.y;
        float d4 = qp1[0]-p2.x, d5 = qp1[1]-p2.y, d6 = qp1[2]-p3.x, d7 = qp1[3]-p3.y;
        float d8 = qp2[0]-p4.x, d9 = qp2[1]-p4.y, dA = qp2[2]-p5.x, dB = qp2[3]-p5.y;
        float d2 = d0*d0+d1*d1+d2a*d2a+d3*d3 + d4*d4+d5*d5+d6*d6+d7*d7 + d8*d8+d9*d9+dA*dA+dB*dB;
        float bv = att[(size_t)h*NSQ + (size_t)ires*NN + jres];
        float lg = qk*S1 + S2*(bv + mterm) - 0.5f*hw[h]*d2;
        att[(size_t)h*NSQ + (size_t)i*NN + j] = lg;
    }
}

// ---- K4c: softmax over j, float4
__global__ __launch_bounds__(192) void k_softmax(float* __restrict__ ws){
    int b = blockIdx.x, t = threadIdx.x;
    float* row = ws + OFF_ATT + (size_t)b*NN;
    floatx4 v = *(floatx4*)(row + t*4);
    float mx = fmaxf(fmaxf(v[0],v[1]), fmaxf(v[2],v[3]));
    for (int off = 32; off; off >>= 1) mx = fmaxf(mx, __shfl_xor(mx, off, 64));
    __shared__ float lsm[3];
    __shared__ float lss[3];
    int w = t >> 6;
    if ((t & 63) == 0) lsm[w] = mx;
    __syncthreads();
    mx = fmaxf(fmaxf(lsm[0], lsm[1]), lsm[2]);
    floatx4 e;
    e[0] = expf(v[0]-mx); e[1] = expf(v[1]-mx); e[2] = expf(v[2]-mx); e[3] = expf(v[3]-mx);
    float s = e[0]+e[1]+e[2]+e[3];
    for (int off = 32; off; off >>= 1) s += __shfl_xor(s, off, 64);
    if ((t & 63) == 0) lss[w] = s;
    __syncthreads();
    s = lss[0] + lss[1] + lss[2];
    float inv = 1.0f / s;
    e[0] *= inv; e[1] *= inv; e[2] *= inv; e[3] *= inv;
    *(floatx4*)(row + t*4) = e;
}

// ---- K5: o and o_pt(global), j-split x3, atomic accumulate (round-2 form)
__global__ __launch_bounds__(256) void k_ov(float* __restrict__ ws){
    __shared__ float wlds[128][41];
    __shared__ float plds[32][128];
    int h = blockIdx.x, it = blockIdx.y, zs = blockIdx.z, t = threadIdx.x;
    const float* proj = ws + OFF_PROJ;
    const float* vpg  = ws + OFF_VPG;
    const float* att  = ws + OFF_ATT + (size_t)h*NSQ;
    int c = t & 63, isub = t >> 6;
    float acc[8] = {0,0,0,0,0,0,0,0};
    for (int jt = zs*2; jt < zs*2+2; jt++){
        __syncthreads();
        for (int ix = t; ix < 128*40; ix += 256){
            int jj = ix / 40, cc = ix % 40;
            int j = jt*128 + jj;
            wlds[jj][cc] = (cc < 16) ? proj[(size_t)j*1152 + 384 + h*16 + cc]
                                     : vpg[(size_t)j*288 + h*24 + (cc - 16)];
        }
        for (int ix = t; ix < 32*128; ix += 256){
            int rr = ix >> 7, jj = ix & 127;
            plds[rr][jj] = att[(size_t)(it*32 + rr)*NN + jt*128 + jj];
        }
        __syncthreads();
        if (c < 40){
            for (int jj = 0; jj < 128; jj += 4){
                float w0 = wlds[jj][c], w1 = wlds[jj+1][c], w2 = wlds[jj+2][c], w3 = wlds[jj+3][c];
                #pragma unroll
                for (int rr = 0; rr < 8; rr++){
                    floatx4 pv = *(floatx4*)&plds[isub*8+rr][jj];
                    acc[rr] += pv[0]*w0 + pv[1]*w1 + pv[2]*w2 + pv[3]*w3;
                }
            }
        }
    }
    if (c < 40){
        float* ocat = ws + OFF_OCAT;
        int col = (c < 16) ? (h*16 + c) : (576 + h*24 + (c - 16));
        for (int rr = 0; rr < 8; rr++){
            int i = it*32 + isub*8 + rr;
            atomicAdd(&ocat[(size_t)i*960 + col], acc[rr]);
        }
    }
}

// ---- K6: o_pair: grid (i, jt). One (h,c) per thread, atomicAdd accumulate.
__global__ __launch_bounds__(384) void k_opair(const int* __restrict__ idx, float* __restrict__ ws){
    __shared__ float plds[12][132];
    __shared__ float pzlds[128][33];
    int i = blockIdx.x, jt = blockIdx.y, t = threadIdx.x;
    int ires = idx[i];
    const float* pzg = ws + OFF_PZ + (size_t)ires*NN*32;
    const float* att = ws + OFF_ATT;
    for (int ix = t; ix < 12*128; ix += 384){
        int hh = ix >> 7, jj = ix & 127;
        plds[hh][jj] = att[(size_t)hh*NSQ + (size_t)i*NN + jt*128 + jj];
    }
    for (int ix = t; ix < 128*32; ix += 384){
        int jj = ix >> 5, cc = ix & 31;
        int jres = idx[jt*128 + jj];
        pzlds[jj][cc] = pzg[(size_t)jres*32 + cc];
    }
    __syncthreads();
    int h = t >> 5, c = t & 31;
    float acc = 0.f;
    #pragma unroll 4
    for (int j = 0; j < 128; j++)
        acc += plds[h][j] * pzlds[j][c];
    float* oc = ws + OFF_OCAT + (size_t)i*960 + 192;
    atomicAdd(&oc[h*32 + c], acc);
}

// ---- K6b: o_pt local frame + norms
__global__ __launch_bounds__(96) void k_ptfin(const float* __restrict__ rot, const float* __restrict__ trans,
                                              float* __restrict__ ws){
    int i = blockIdx.x, p = threadIdx.x;
    float* base = ws + OFF_OCAT + (size_t)i*960;
    float* pt = base + 576 + p*3;
    float x = pt[0] - trans[i*3+0];
    float y = pt[1] - trans[i*3+1];
    float z = pt[2] - trans[i*3+2];
    const float* R = rot + (size_t)i*9;
    float lx = R[0]*x + R[3]*y + R[6]*z;
    float ly = R[1]*x + R[4]*y + R[7]*z;
    float lz = R[2]*x + R[5]*y + R[8]*z;
    pt[0] = lx; pt[1] = ly; pt[2] = lz;
    base[864 + p] = sqrtf(lx*lx + ly*ly + lz*lz + EPS_);
}

// ---- K7: final GEMM, k-split x4, 8x2 register tile, atomic into zeroed out
__global__ __launch_bounds__(256) void k_out(const float* __restrict__ Wout, const float* __restrict__ Woutb,
                                             const float* __restrict__ Woutp, float* __restrict__ ws,
                                             float* __restrict__ out){
    __shared__ float olds[32][244];
    int it = blockIdx.x, ct = blockIdx.y, kc = blockIdx.z, t = threadIdx.x;
    const float* ocat = ws + OFF_OCAT;
    for (int ix = t; ix < 32*240; ix += 256){
        int r = ix / 240, kk = ix % 240;
        olds[r][kk] = ocat[(size_t)(it*32 + r)*960 + kc*240 + kk];
    }
    __syncthreads();
    int cl = t & 63, ig = t >> 6;
    int c0 = ct*128 + cl, c1 = c0 + 64;
    float acc0[8], acc1[8];
    #pragma unroll
    for (int r=0;r<8;r++){ acc0[r]=0; acc1[r]=0; }
    for (int kk = 0; kk < 240; kk += 4){
        float w0[4], w1[4];
        #pragma unroll
        for (int u = 0; u < 4; u++){
            int k = kc*240 + kk + u;
            const float* wrow = (k < 192) ? (Wout  + (size_t)k*CS)
                              : (k < 576) ? (Woutb + (size_t)(k-192)*CS)
                                          : (Woutp + (size_t)(k-576)*CS);
            w0[u] = wrow[c0]; w1[u] = wrow[c1];
        }
        #pragma unroll
        for (int r = 0; r < 8; r++){
            floatx4 ov = *(const floatx4*)&olds[ig*8 + r][kk];
            acc0[r] += ov[0]*w0[0] + ov[1]*w0[1] + ov[2]*w0[2] + ov[3]*w0[3];
            acc1[r] += ov[0]*w1[0] + ov[1]*w1[1] + ov[2]*w1[2] + ov[3]*w1[3];
        }
    }
    for (int r = 0; r < 8; r++){
        int i = it*32 + ig*8 + r;
        atomicAdd(&out[(size_t)i*CS + c0], acc0[r]);
        atomicAdd(&out[(size_t)i*CS + c1], acc1[r]);
    }
}

extern "C" void kernel_launch(void* const* d_in, const int* in_sizes, int n_in,
                              void* d_out, int out_size, void* d_ws, size_t ws_size,
                              hipStream_t stream){
    const float* s     = (const float*)d_in[0];
    const float* z     = (const float*)d_in[1];
    const float* rot   = (const float*)d_in[2];
    const float* trans = (const float*)d_in[3];
    const float* smask = (const float*)d_in[4];
    const float* gs    = (const float*)d_in[5];
    const float* bs    = (const float*)d_in[6];
    const float* gz    = (const float*)d_in[7];
    const float* bz    = (const float*)d_in[8];
    const float* Wq    = (const float*)d_in[9];
    const float* Wk    = (const float*)d_in[10];
    const float* Wv    = (const float*)d_in[11];
    const float* Wqp   = (const float*)d_in[12];
    const float* Wkp   = (const float*)d_in[13];
    const float* Wvp   = (const float*)d_in[14];
    const float* Wb    = (const float*)d_in[15];
    const float* Wdz   = (const float*)d_in[16];
    const float* hwin  = (const float*)d_in[17];
    const float* Wout  = (const float*)d_in[18];
    const float* Woutb = (const float*)d_in[19];
    const float* Woutp = (const float*)d_in[20];
    const int*   idx   = (const int*)d_in[21];
    float* ws  = (float*)d_ws;
    float* out = (float*)d_out;

    k_setup  <<<4057, 256, 0, stream>>>(Wb, Wdz, hwin, ws, out);
    k_lns    <<<768, 128, 0, stream>>>(s, gs, bs, ws);
    k_proj   <<<dim3(48, 9), 256, 0, stream>>>(Wq, Wk, Wv, Wqp, Wkp, Wvp, ws);
    k_pts    <<<768, 192, 0, stream>>>(rot, trans, ws);
    k_z      <<<9216, 256, 0, stream>>>(z, gz, bz, ws);
    k_logits <<<dim3(96, 24), 256, 0, stream>>>(smask, idx, ws);
    k_softmax<<<9216, 192, 0, stream>>>(ws);
    k_ov     <<<dim3(12, 24, 3), 256, 0, stream>>>(ws);
    k_opair  <<<dim3(768, 6), 384, 0, stream>>>(idx, ws);
    k_ptfin  <<<768, 96, 0, stream>>>(rot, trans, ws);
    k_out    <<<dim3(24, 3, 4), 256, 0, stream>>>(Wout, Woutb, Woutp, ws, out);
}